// Round 14
// baseline (299.462 us; speedup 1.0000x reference)
//
#include <hip/hip_runtime.h>
#include <hip/hip_fp16.h>
#include <math.h>

// Problem constants
#define B 4
#define C 21
#define NP 11               // f16 channel pairs (ch 2k, 2k+1; pair 10 high = pad)
#define H 256
#define W 256
#define HW (H*W)            // 65536
#define NPIX (B*HW)         // 262144
#define NB2 (B*NP*HW)       // 2883584 packed uint elements

// update tile: 16 wide x 32 tall, 256 threads, 2 rows per thread
#define TSX 16
#define TSY 32
#define R 6
#define HXC 28              // halo cols
#define HXP 29              // padded LDS row stride
#define HYR 44              // halo rows
#define NSU (HXC*HYR)       // 1232 records
#define NSPP (HXP*HYR)      // 1276 padded slots

#define C2F ((float)(1.4426950408889634 / 338.0))   // log2(e)/338
#define L2E 1.4426950408889634f

// weight table: [tile(512)][15 rows][512 px][16B]; rows 13,14 zeroed (pipeline pad)
#define WT_ROWS 15
#define WT_TILE (WT_ROWS*512)    // uint4 per tile

// e5m2 unpack selectors: perm(hi=qword, lo=0, sel) -> bytes [0,q_even,0,q_odd]
// = half2 (q_even<<8, q_odd<<8) = exact e5m2->f16
#define SEL01 0x05000400u
#define SEL23 0x07000600u

// Gaussian-fused kernel geometry
#define GOY 64
#define GTR (GOY + 18)      // 82 T rows
#define GTS 17              // padded quad stride

union U4 { uint4 u; __half2 h[4]; };
union Hu { unsigned int u32; __half2 h; };

#if defined(__has_builtin)
#if __has_builtin(__builtin_amdgcn_udot4)
#define USE_UDOT 1
#endif
#endif

__device__ __forceinline__ float fexp2(float x) {
    float r;
    asm("v_exp_f32 %0, %1" : "=v"(r) : "v"(x));
    return r;
}

typedef __fp16 f16x2 __attribute__((ext_vector_type(2)));
__device__ __forceinline__ __half2 h2bcast(float w) {
    f16x2 t = __builtin_amdgcn_cvt_pkrtz(w, w);   // exact: w is an integer 0..255
    return *(__half2*)&t;
}

// exact e5m2 pair -> f16 pair via byte permute (e5m2 == f16 top byte)
__device__ __forceinline__ __half2 pe5(unsigned int qw, unsigned int sel) {
    Hu h; h.u32 = __builtin_amdgcn_perm(qw, 0u, sel);
    return h.h;
}

// two f32 -> packed e5m2 bytes (RN via f16 + round-shift; inputs in [0,1])
__device__ __forceinline__ unsigned int pk_e5m2(float a, float b) {
    f16x2 t = __builtin_amdgcn_cvt_pkrtz(a, b);
    unsigned int h = *(unsigned int*)&t;
    unsigned int lo = ((h & 0xFFFFu) + 0x80u) >> 8;
    unsigned int hi = (((h >> 16) & 0xFFFFu) + 0x80u) >> 8;
    return lo | (hi << 8);        // byte0 = e(a), byte1 = e(b)
}

// ---------------------------------------------------------------------------
// Init: U packed f16; Q0 = softmax(-U) written f16 (for gauss) + e5m2 (for update).
// Thread 0 also fills the Gaussian tap table.
__global__ __launch_bounds__(256) void k_init(const float* __restrict__ logits,
                                              unsigned int* __restrict__ Upk,
                                              unsigned int* __restrict__ Qp,
                                              uint4* __restrict__ Q8a,
                                              uint2* __restrict__ Q8b,
                                              float* __restrict__ kt) {
    int p = blockIdx.x * 256 + threadIdx.x;
    if (p == 0) {
        float e[19]; float s0 = 0.f;
        for (int i = 0; i < 19; ++i) {
            double d = (double)(i - 9);
            e[i] = (float)exp(-(d*d) / 18.0);
            s0 += e[i];
        }
        for (int i = 0; i < 19; ++i) kt[i] = e[i] / s0;
        float k9 = e[9] / s0;
        kt[19] = k9 * k9;
        kt[20] = 1.f - k9 * k9;
    }
    int b = p >> 16, g = p & (HW - 1);
    const float* lp = logits + (size_t)b * C * HW + g;

    float v[C];
    float m = -1e30f;
#pragma unroll
    for (int c = 0; c < C; ++c) { v[c] = lp[c*HW]; m = fmaxf(m, v[c]); }
    float s = 0.f;
#pragma unroll
    for (int c = 0; c < C; ++c) { v[c] = __expf(v[c] - m); s += v[c]; }
    float inv = 1.f / s;

    float u[C];
    float m2 = -1e30f;
#pragma unroll
    for (int c = 0; c < C; ++c) {
        float sm = fminf(fmaxf(v[c] * inv, 1e-5f), 1.f);
        float uu = -__logf(sm);
        u[c] = uu;
        m2 = fmaxf(m2, -uu);
    }
    float s2 = 0.f;
    float q[C + 1];
#pragma unroll
    for (int c = 0; c < C; ++c) { q[c] = __expf(-u[c] - m2); s2 += q[c]; }
    float inv2 = 1.f / s2;
#pragma unroll
    for (int c = 0; c < C; ++c) q[c] *= inv2;
    q[C] = 0.f;

    unsigned int* Ub = Upk + (size_t)b * NP * HW + g;
    unsigned int* Qb = Qp + (size_t)b * NP * HW + g;
#pragma unroll
    for (int k = 0; k < NP; ++k) {
        float ua = u[2*k];
        float ub = (2*k + 1 < C) ? u[2*k + 1] : 0.f;
        Hu xu; xu.h = __floats2half2_rn(ua, ub);
        Ub[k*HW] = xu.u32;
        Hu xq; xq.h = __floats2half2_rn(q[2*k], q[2*k+1]);
        Qb[k*HW] = xq.u32;
    }
    unsigned int w8[6];
#pragma unroll
    for (int j = 0; j < 5; ++j)
        w8[j] = pk_e5m2(q[4*j], q[4*j+1]) | (pk_e5m2(q[4*j+2], q[4*j+3]) << 16);
    w8[5] = pk_e5m2(q[20], 0.f);
    Q8a[p] = make_uint4(w8[0], w8[1], w8[2], w8[3]);
    Q8b[p] = make_uint2(w8[4], w8[5]);
}

// ---------------------------------------------------------------------------
// Precompute bilateral weights (image-only, iteration-invariant), u8-quantized.
__global__ __launch_bounds__(256) void k_wgt(const float* __restrict__ img,
                                             uint4* __restrict__ WT) {
    __shared__ float4 IRGB[NSU];

    int blk = blockIdx.x;
    int b = blk >> 7;
    int tile = blk & 127;
    int ty0 = (tile >> 4) * TSY;
    int tx0 = (tile & 15) * TSX;
    int tid = threadIdx.x;

    const float* Ib = img + (size_t)b * 3 * HW;
    for (int s = tid; s < NSU; s += 256) {
        int ly = s / HXC, lx = s - ly * HXC;
        int gy = ty0 + ly - R, gx = tx0 + lx - R;
        bool in = ((unsigned)gy < (unsigned)H) && ((unsigned)gx < (unsigned)W);
        int g = gy * W + gx;
        float r = 0.f, gg = 0.f, bb = 0.f;
        if (in) {
            r  = floorf(fminf(fmaxf(Ib[g]        * 255.f, 0.f), 255.f));
            gg = floorf(fminf(fmaxf(Ib[HW + g]   * 255.f, 0.f), 255.f));
            bb = floorf(fminf(fmaxf(Ib[2*HW + g] * 255.f, 0.f), 255.f));
        }
        IRGB[s] = make_float4(r, gg, bb, 0.f);
    }
    __syncthreads();

    int x = tid & 15, ry = tid >> 4, r0 = 2 * ry;
    int cp0 = (r0 + R) * HXC + x + R;
    float4 c0 = IRGB[cp0];
    float4 c1 = IRGB[cp0 + HXC];
    float DCr = c1.x - c0.x, DCg = c1.y - c0.y, DCb = c1.z - c0.z;
    float DR2 = 2.f*DCr, DG2 = 2.f*DCg, DB2 = 2.f*DCb;
    float DC2 = DCr*DCr + DCg*DCg + DCb*DCb;

    uint4* base = WT + (size_t)blk * WT_TILE;
    int px0 = r0 * 16 + x;

    for (int dyy = 0; dyy < 14; ++dyy) {
        int t0 = dyy - 6, t1 = dyy - 7;
        float a0 = -(float)(t0*t0) * C2F;
        float a1 = -(float)(t1*t1) * C2F;
        unsigned int wa0[4] = {0u,0u,0u,0u}, wa1[4] = {0u,0u,0u,0u};
        int rowb = (r0 + dyy) * HXC + x;
#pragma unroll
        for (int dx = 0; dx < 13; ++dx) {
            float4 n = IRGB[rowb + dx];
            float d0r = c0.x - n.x, d0g = c0.y - n.y, d0b = c0.z - n.z;
            float ss0 = fmaf(d0r, d0r, fmaf(d0g, d0g, d0b * d0b));
            float ss1 = fmaf(DR2, d0r, fmaf(DG2, d0g, fmaf(DB2, d0b, ss0 + DC2)));
            float cc = -(float)((dx - 6) * (dx - 6)) * C2F;
            float w0 = fexp2(fmaf(ss0, -C2F, a0 + cc));
            float w1 = fexp2(fmaf(ss1, -C2F, a1 + cc));
            if (dyy == 6 && dx == 6) w0 = 0.f;   // exact center exclusion
            if (dyy == 7 && dx == 6) w1 = 0.f;
            unsigned int u0 = (unsigned int)fmaf(w0, 255.f, 0.5f);
            unsigned int u1 = (unsigned int)fmaf(w1, 255.f, 0.5f);
            wa0[dx >> 2] |= u0 << (8 * (dx & 3));
            wa1[dx >> 2] |= u1 << (8 * (dx & 3));
        }
        if (dyy <= 12) base[dyy*512 + px0]          = make_uint4(wa0[0], wa0[1], wa0[2], wa0[3]);
        if (dyy >= 1)  base[(dyy-1)*512 + px0 + 16] = make_uint4(wa1[0], wa1[1], wa1[2], wa1[3]);
    }
    uint4 z = make_uint4(0u, 0u, 0u, 0u);
    base[13*512 + px0] = z;  base[13*512 + px0 + 16] = z;
    base[14*512 + px0] = z;  base[14*512 + px0 + 16] = z;
}

// ---------------------------------------------------------------------------
// Fused separable Gaussian + message: MG = (conv - w0*Q)*(1/(1-w0)).
__global__ __launch_bounds__(256) void k_gauss(const unsigned int* __restrict__ Q,
                                               unsigned int* __restrict__ MG,
                                               const float* __restrict__ kt) {
    __shared__ uint4 T[GTR * GTS];
    __shared__ float kf[21];

    int tid = threadIdx.x;
    if (tid < 21) kf[tid] = kt[tid];
    __syncthreads();

    __half2 kh[19];
#pragma unroll
    for (int j = 0; j < 19; ++j) kh[j] = __float2half2_rn(kf[j]);

    int blk = blockIdx.x;
    int pl  = blk >> 4;
    int sub = blk & 15;
    int y0 = (sub >> 2) * GOY;
    int x0 = (sub & 3) * 64;
    const unsigned int* base = Q + (size_t)pl * HW;

    for (int s = tid; s < GTR * 16; s += 256) {
        int row = s >> 4;
        int q   = s & 15;
        int yy = y0 + row - 9;
        U4 o;
        o.u = make_uint4(0u, 0u, 0u, 0u);
        if ((unsigned)yy < (unsigned)H) {
            int xb = x0 + q * 4;
            const unsigned int* rp = base + yy * W;
            U4 ch[7];
#pragma unroll
            for (int c2 = 0; c2 < 7; ++c2) {
                int xq = xb - 12 + c2 * 4;
                if ((unsigned)xq < (unsigned)W) ch[c2].u = *(const uint4*)(rp + xq);
                else ch[c2].u = make_uint4(0u, 0u, 0u, 0u);
            }
            const __half2* v = (const __half2*)ch;
#pragma unroll
            for (int i = 0; i < 4; ++i) {
                __half2 acc = __float2half2_rn(0.f);
#pragma unroll
                for (int j = 0; j < 19; ++j) acc = __hfma2(kh[j], v[i + 3 + j], acc);
                o.h[i] = acc;
            }
        }
        T[row * GTS + q] = o.u;
    }
    __syncthreads();

    __half2 nw0  = __float2half2_rn(-kf[19]);
    __half2 inv1 = __float2half2_rn(1.f / kf[20]);
    int q  = tid & 15;
    int rg = tid >> 4;
    int r0 = rg * 4;

    __half2 acc[4][4];
#pragma unroll
    for (int i = 0; i < 4; ++i)
#pragma unroll
        for (int qd = 0; qd < 4; ++qd) acc[i][qd] = __float2half2_rn(0.f);

#pragma unroll
    for (int j = 0; j < 22; ++j) {
        U4 f; f.u = T[(r0 + j) * GTS + q];
#pragma unroll
        for (int i = 0; i < 4; ++i) {
            int tap = j - i;
            if (tap >= 0 && tap <= 18) {
#pragma unroll
                for (int qd = 0; qd < 4; ++qd)
                    acc[i][qd] = __hfma2(kh[tap], f.h[qd], acc[i][qd]);
            }
        }
    }

#pragma unroll
    for (int i = 0; i < 4; ++i) {
        size_t e = (size_t)pl * HW + (y0 + r0 + i) * W + x0 + q * 4;
        U4 qq; qq.u = *(const uint4*)(Q + e);
        U4 o;
#pragma unroll
        for (int qd = 0; qd < 4; ++qd)
            o.h[qd] = __hmul2(__hfma2(nw0, qq.h[qd], acc[i][qd]), inv1);
        *(uint4*)(MG + e) = o.u;
    }
}

// ---------------------------------------------------------------------------
// Bilateral message: Q staged as e5m2 (24B/record -> ~30KB LDS -> 4-5 blocks/CU);
// exact e5m2->f16 unpack via one v_perm per channel pair; u8 weights from WT.
__global__ __launch_bounds__(256, 4) void k_update(const uint4* __restrict__ Q8a,
                                                   const uint2* __restrict__ Q8b,
                                                   const unsigned int* __restrict__ Upk,
                                                   const unsigned int* __restrict__ MG,
                                                   const uint4* __restrict__ WT,
                                                   unsigned int* __restrict__ Qn,
                                                   uint4* __restrict__ Q8na,
                                                   uint2* __restrict__ Q8nb,
                                                   const int* __restrict__ labels,
                                                   float* __restrict__ part) {
    __shared__ uint4 L16[NSPP];   // ch 0..15 e5m2 (20416 B)
    __shared__ uint2 L5[NSPP];    // ch 16..20 + pad (10208 B) -> 29.9 KB
    __shared__ float red[4];

    int blk = blockIdx.x;
    int b = blk >> 7;
    int tile = blk & 127;
    int ty0 = (tile >> 4) * TSY;
    int tx0 = (tile & 15) * TSX;
    int tid = threadIdx.x;

    const uint4* Qa = Q8a + (size_t)b * HW;
    const uint2* Qb = Q8b + (size_t)b * HW;

    // staging: 2 loads + 2 LDS stores per record
#pragma unroll
    for (int i = 0; i < 5; ++i) {
        int s = tid + i * 256;
        if (s < NSU) {
            int ly = s / HXC;
            int lx = s - ly * HXC;
            int gy = ty0 + ly - R;
            int gx = tx0 + lx - R;
            bool in = ((unsigned)gy < (unsigned)H) && ((unsigned)gx < (unsigned)W);
            int g = gy * W + gx;
            uint4 a = in ? Qa[g] : make_uint4(0u, 0u, 0u, 0u);
            uint2 c = in ? Qb[g] : make_uint2(0u, 0u);
            int p = ly * HXP + lx;
            L16[p] = a;
            L5[p]  = c;
        }
    }
    __syncthreads();

    int x = tid & 15;
    int ry = tid >> 4;                // 0..15 -> rows 2ry, 2ry+1
    int r0 = 2 * ry;
    int g0 = (ty0 + r0) * W + (tx0 + x);
    int px0 = r0 * 16 + x;

    // epilogue prefetch
    const unsigned int* Ub = Upk + (size_t)b * NP * HW;
    const unsigned int* Mb = MG + (size_t)b * NP * HW;
    unsigned int pfU[2][NP], pfM[2][NP];
#pragma unroll
    for (int k = 0; k < NP; ++k) {
        pfU[0][k] = Ub[k*HW + g0];       pfM[0][k] = Mb[k*HW + g0];
        pfU[1][k] = Ub[k*HW + g0 + W];   pfM[1][k] = Mb[k*HW + g0 + W];
    }

    const uint4* wbase = WT + (size_t)blk * WT_TILE;

    __half2 m0[NP], m1[NP];
#pragma unroll
    for (int k = 0; k < NP; ++k) { m0[k] = __float2half2_rn(0.f); m1[k] = m0[k]; }
#ifdef USE_UDOT
    unsigned int ws0i = 0u, ws1i = 0u;
#else
    float ws0f = 0.f, ws1f = 0.f;
#endif

    uint4 w0r = wbase[px0];
    uint4 w1r = make_uint4(0u, 0u, 0u, 0u);

    for (int dyy = 0; dyy < 14; ++dyy) {
        uint4 nwa = wbase[(dyy + 1) * 512 + px0];
        uint4 nwb = wbase[dyy * 512 + px0 + 16];
#ifdef USE_UDOT
        ws0i = __builtin_amdgcn_udot4(w0r.x, 0x01010101u, ws0i, false);
        ws0i = __builtin_amdgcn_udot4(w0r.y, 0x01010101u, ws0i, false);
        ws0i = __builtin_amdgcn_udot4(w0r.z, 0x01010101u, ws0i, false);
        ws0i = __builtin_amdgcn_udot4(w0r.w, 0x01010101u, ws0i, false);
        ws1i = __builtin_amdgcn_udot4(w1r.x, 0x01010101u, ws1i, false);
        ws1i = __builtin_amdgcn_udot4(w1r.y, 0x01010101u, ws1i, false);
        ws1i = __builtin_amdgcn_udot4(w1r.z, 0x01010101u, ws1i, false);
        ws1i = __builtin_amdgcn_udot4(w1r.w, 0x01010101u, ws1i, false);
#endif
        int rowb = (r0 + dyy) * HXP + x;
#pragma unroll
        for (int dx = 0; dx < 13; ++dx) {
            int p = rowb + dx;
            U4 A; A.u = L16[p];
            uint2 cx = L5[p];

            unsigned int q0 = (dx < 4) ? w0r.x : (dx < 8) ? w0r.y : (dx < 12) ? w0r.z : w0r.w;
            unsigned int q1 = (dx < 4) ? w1r.x : (dx < 8) ? w1r.y : (dx < 12) ? w1r.z : w1r.w;
            float w0 = (float)((q0 >> (8 * (dx & 3))) & 0xffu);
            float w1 = (float)((q1 >> (8 * (dx & 3))) & 0xffu);
#ifndef USE_UDOT
            ws0f += w0; ws1f += w1;
#endif
            __half2 wh0 = h2bcast(w0);
            __half2 wh1 = h2bcast(w1);

            __half2 v0 = pe5(A.u.x, SEL01);
            __half2 v1 = pe5(A.u.x, SEL23);
            __half2 v2 = pe5(A.u.y, SEL01);
            __half2 v3 = pe5(A.u.y, SEL23);
            __half2 v4 = pe5(A.u.z, SEL01);
            __half2 v5 = pe5(A.u.z, SEL23);
            __half2 v6 = pe5(A.u.w, SEL01);
            __half2 v7 = pe5(A.u.w, SEL23);
            __half2 v8 = pe5(cx.x, SEL01);
            __half2 v9 = pe5(cx.x, SEL23);
            __half2 va = pe5(cx.y, SEL01);

            m0[0] = __hfma2(wh0, v0, m0[0]);   m1[0] = __hfma2(wh1, v0, m1[0]);
            m0[1] = __hfma2(wh0, v1, m0[1]);   m1[1] = __hfma2(wh1, v1, m1[1]);
            m0[2] = __hfma2(wh0, v2, m0[2]);   m1[2] = __hfma2(wh1, v2, m1[2]);
            m0[3] = __hfma2(wh0, v3, m0[3]);   m1[3] = __hfma2(wh1, v3, m1[3]);
            m0[4] = __hfma2(wh0, v4, m0[4]);   m1[4] = __hfma2(wh1, v4, m1[4]);
            m0[5] = __hfma2(wh0, v5, m0[5]);   m1[5] = __hfma2(wh1, v5, m1[5]);
            m0[6] = __hfma2(wh0, v6, m0[6]);   m1[6] = __hfma2(wh1, v6, m1[6]);
            m0[7] = __hfma2(wh0, v7, m0[7]);   m1[7] = __hfma2(wh1, v7, m1[7]);
            m0[8] = __hfma2(wh0, v8, m0[8]);   m1[8] = __hfma2(wh1, v8, m1[8]);
            m0[9] = __hfma2(wh0, v9, m0[9]);   m1[9] = __hfma2(wh1, v9, m1[9]);
            m0[10] = __hfma2(wh0, va, m0[10]); m1[10] = __hfma2(wh1, va, m1[10]);
        }
        w0r = nwa;
        w1r = nwb;
    }

#ifdef USE_UDOT
    float ws0 = (float)ws0i, ws1 = (float)ws1i;
#else
    float ws0 = ws0f, ws1 = ws1f;
#endif

    // Epilogue (log2-domain softmax); write f16 Q + e5m2 Q, or NLL on last iter.
    unsigned int* Qo = Qn + (size_t)b * NP * HW;
    uint4* Qoa = Q8na + (size_t)b * HW;
    uint2* Qob = Q8nb + (size_t)b * HW;

    float nll = 0.f;
#pragma unroll
    for (int px = 0; px < 2; ++px) {
        const __half2* m = px ? m1 : m0;
        float inv = 1.f / ((px ? ws1 : ws0) + 2.55e-6f);
        int g = g0 + px * W;
        float sv[C + 1];
        float mm = -1e30f;
#pragma unroll
        for (int k = 0; k < NP; ++k) {
            float2 mf = __half22float2(m[k]);
            Hu mgu; mgu.u32 = pfM[px][k];
            float2 mgf = __half22float2(mgu.h);
            Hu uu; uu.u32 = pfU[px][k];
            float2 uf = __half22float2(uu.h);
            int c0 = 2 * k;
            float v0 = fmaf(-L2E, uf.x, fmaf(3.f*L2E, mgf.x, (10.f*L2E) * (mf.x * inv)));
            sv[c0] = v0; mm = fmaxf(mm, v0);
            if (c0 + 1 < C) {
                float v1 = fmaf(-L2E, uf.y, fmaf(3.f*L2E, mgf.y, (10.f*L2E) * (mf.y * inv)));
                sv[c0+1] = v1; mm = fmaxf(mm, v1);
            }
        }
        float s = 0.f;
#pragma unroll
        for (int c = 0; c < C; ++c) { sv[c] = fexp2(sv[c] - mm); s += sv[c]; }
        if (labels) {
            int lab = labels[(size_t)b * HW + g];
            float qsum = 0.f, ql = 1e-8f;
#pragma unroll
            for (int c = 0; c < C; ++c) {
                float qc = sv[c] / s + 1e-8f;
                qsum += qc;
                if (c == lab) ql = qc;
            }
            nll += __logf(qsum) - __logf(ql);
        } else {
            float is = 1.f / s;
#pragma unroll
            for (int c = 0; c < C; ++c) sv[c] *= is;
            sv[C] = 0.f;
#pragma unroll
            for (int k = 0; k < NP; ++k) {
                Hu xh; xh.h = __floats2half2_rn(sv[2*k], sv[2*k+1]);
                Qo[k*HW + g] = xh.u32;
            }
            unsigned int w8[6];
#pragma unroll
            for (int j = 0; j < 5; ++j)
                w8[j] = pk_e5m2(sv[4*j], sv[4*j+1]) | (pk_e5m2(sv[4*j+2], sv[4*j+3]) << 16);
            w8[5] = pk_e5m2(sv[20], 0.f);
            Qoa[g] = make_uint4(w8[0], w8[1], w8[2], w8[3]);
            Qob[g] = make_uint2(w8[4], w8[5]);
        }
    }

    if (labels) {
#pragma unroll
        for (int off = 32; off > 0; off >>= 1) nll += __shfl_down(nll, off);
        int lane = tid & 63, wv = tid >> 6;
        if (lane == 0) red[wv] = nll;
        __syncthreads();
        if (tid == 0) part[blk] = red[0] + red[1] + red[2] + red[3];
    }
}

// ---------------------------------------------------------------------------
__global__ __launch_bounds__(256) void k_final(const float* __restrict__ part,
                                               float* __restrict__ out) {
    int tid = threadIdx.x;
    float s = part[tid] + part[tid + 256];
#pragma unroll
    for (int off = 32; off > 0; off >>= 1) s += __shfl_down(s, off);
    __shared__ float red[4];
    int lane = tid & 63, wv = tid >> 6;
    if (lane == 0) red[wv] = s;
    __syncthreads();
    if (tid == 0) out[0] = (red[0] + red[1] + red[2] + red[3]) / (float)NPIX;
}

// ---------------------------------------------------------------------------
extern "C" void kernel_launch(void* const* d_in, const int* in_sizes, int n_in,
                              void* d_out, int out_size, void* d_ws, size_t ws_size,
                              hipStream_t stream) {
    const float* logits = (const float*)d_in[0];
    const float* images = (const float*)d_in[1];
    const int*   labels = (const int*)d_in[2];
    float* out = (float*)d_out;

    unsigned int* ws = (unsigned int*)d_ws;
    unsigned int* Upk = ws;                     // NB2
    unsigned int* QA  = ws +   (size_t)NB2;     // NB2 (f16 ping)
    unsigned int* QB  = ws + 2*(size_t)NB2;     // NB2 (f16 pong)
    unsigned int* Mpk = ws + 3*(size_t)NB2;     // NB2
    uint4*        WT  = (uint4*)(ws + 4*(size_t)NB2);        // 512*15*512 uint4 = 62.9MB
    uint4*        Q8Aa = WT + (size_t)512*WT_TILE;           // NPIX uint4 (e5m2 ping lo)
    uint4*        Q8Ba = Q8Aa + (size_t)NPIX;                // NPIX uint4 (e5m2 pong lo)
    uint2*        Q8Ab = (uint2*)(Q8Ba + (size_t)NPIX);      // NPIX uint2 (ping hi)
    uint2*        Q8Bb = Q8Ab + (size_t)NPIX;                // NPIX uint2 (pong hi)
    float*        KT  = (float*)(Q8Bb + (size_t)NPIX);       // 64 f32
    float*        PART = KT + 64;                            // 512 f32

    k_init<<<NPIX/256, 256, 0, stream>>>(logits, Upk, QA, Q8Aa, Q8Ab, KT);
    k_wgt<<<B*128, 256, 0, stream>>>(images, WT);

    unsigned int* cur = QA;  unsigned int* oth = QB;
    uint4* c8a = Q8Aa;       uint4* o8a = Q8Ba;
    uint2* c8b = Q8Ab;       uint2* o8b = Q8Bb;
    for (int it = 0; it < 5; ++it) {
        k_gauss<<<B*NP*16, 256, 0, stream>>>(cur, Mpk, KT);
        k_update<<<B*128, 256, 0, stream>>>(c8a, c8b, Upk, Mpk, WT, oth, o8a, o8b,
                                            (it == 4) ? labels : nullptr, PART);
        unsigned int* t = cur; cur = oth; oth = t;
        uint4* ta = c8a; c8a = o8a; o8a = ta;
        uint2* tb = c8b; c8b = o8b; o8b = tb;
    }

    k_final<<<1, 256, 0, stream>>>(PART, out);
    (void)in_sizes; (void)n_in; (void)out_size; (void)ws_size;
}